// Round 5
// baseline (338.203 us; speedup 1.0000x reference)
//
#include <hip/hip_runtime.h>
#include <hip/hip_bf16.h>
#include <stdint.h>

typedef __attribute__((ext_vector_type(8))) short short8;
typedef __attribute__((ext_vector_type(4))) float floatx4;
typedef __attribute__((ext_vector_type(8))) int int8v;
typedef __attribute__((ext_vector_type(4))) int int4v;

__device__ __forceinline__ ushort f2b(float f) {
    union { float f; uint32_t u; } v; v.f = f;
    uint32_t r = (v.u + 0x7fffu + ((v.u >> 16) & 1u)) >> 16;
    return (ushort)r;
}
__device__ __forceinline__ float b2f(ushort b) {
    union { uint32_t u; float f; } v; v.u = ((uint32_t)b) << 16;
    return v.f;
}
__device__ __forceinline__ uint8_t f2fp8(float f) {
    return (uint8_t)(__builtin_amdgcn_cvt_pk_fp8_f32(f, f, 0, false) & 0xff);
}

__device__ __forceinline__ void gl_lds16(const void* g, void* l) {
    __builtin_amdgcn_global_load_lds(
        (const __attribute__((address_space(1))) void*)g,
        (__attribute__((address_space(3))) void*)l, 16, 0, 0);
}

// ---------------- elementwise f32 -> fp8 e4m3 (*s) ----------------
__global__ __launch_bounds__(256) void convert_f32_fp8(const float* __restrict__ in,
                                                       uint8_t* __restrict__ out,
                                                       int n4, float s) {
    int i = blockIdx.x * 256 + threadIdx.x;
    if (i < n4) {
        float4 v = ((const float4*)in)[i];
        int p = __builtin_amdgcn_cvt_pk_fp8_f32(v.x * s, v.y * s, 0, false);
        p = __builtin_amdgcn_cvt_pk_fp8_f32(v.z * s, v.w * s, p, true);
        ((uint32_t*)out)[i] = p;
    }
}

// ---------------- transpose f32[R,C] -> fp8[C,R] (*s) ----------------
__global__ __launch_bounds__(256) void transpose_f32_to_fp8(const float* __restrict__ in,
                                                            uint8_t* __restrict__ out,
                                                            int R, int Cc, float s) {
    __shared__ uint8_t t[32][36];
    int bx = blockIdx.x * 32, by = blockIdx.y * 32;
    int tx = threadIdx.x & 31, ty = threadIdx.x >> 5;
    #pragma unroll
    for (int i = 0; i < 32; i += 8)
        t[ty + i][tx] = f2fp8(in[(size_t)(by + ty + i) * Cc + bx + tx] * s);
    __syncthreads();
    #pragma unroll
    for (int i = 0; i < 32; i += 8)
        out[(size_t)(bx + ty + i) * R + by + tx] = t[tx][ty + i];
}

// ---------------- transpose bf16[R,C] -> fp8[C,R] (*s) ----------------
__global__ __launch_bounds__(256) void transpose_bf16_to_fp8(const ushort* __restrict__ in,
                                                             uint8_t* __restrict__ out,
                                                             int R, int Cc, float s) {
    __shared__ uint8_t t[32][36];
    int bx = blockIdx.x * 32, by = blockIdx.y * 32;
    int tx = threadIdx.x & 31, ty = threadIdx.x >> 5;
    #pragma unroll
    for (int i = 0; i < 32; i += 8)
        t[ty + i][tx] = f2fp8(b2f(in[(size_t)(by + ty + i) * Cc + bx + tx]) * s);
    __syncthreads();
    #pragma unroll
    for (int i = 0; i < 32; i += 8)
        out[(size_t)(bx + ty + i) * R + by + tx] = t[tx][ty + i];
}

// ---------------- transpose f32[R,C] -> bf16[C,R] ----------------
__global__ __launch_bounds__(256) void transpose_f32_to_bf16(const float* __restrict__ in,
                                                             ushort* __restrict__ out,
                                                             int R, int Cc) {
    __shared__ ushort t[32][33];
    int bx = blockIdx.x * 32, by = blockIdx.y * 32;
    int tx = threadIdx.x & 31, ty = threadIdx.x >> 5;
    #pragma unroll
    for (int i = 0; i < 32; i += 8)
        t[ty + i][tx] = f2b(in[(size_t)(by + ty + i) * Cc + bx + tx]);
    __syncthreads();
    #pragma unroll
    for (int i = 0; i < 32; i += 8)
        out[(size_t)(bx + ty + i) * R + by + tx] = t[tx][ty + i];
}

// ---------------- row L2-normalize f32 in -> bf16 out ----------------
__global__ __launch_bounds__(256) void normalize_f32_to_bf16(const float* __restrict__ in,
                                                             ushort* __restrict__ out, int D) {
    int row = blockIdx.x;
    const float* x = in + (size_t)row * D;
    float s = 0.0f;
    for (int i = threadIdx.x; i < D; i += 256) { float t = x[i]; s += t * t; }
    __shared__ float sm[4];
    #pragma unroll
    for (int off = 32; off; off >>= 1) s += __shfl_down(s, off, 64);
    if ((threadIdx.x & 63) == 0) sm[threadIdx.x >> 6] = s;
    __syncthreads();
    float inv = 1.0f / sqrtf(sm[0] + sm[1] + sm[2] + sm[3]);
    ushort* o = out + (size_t)row * D;
    for (int i = threadIdx.x; i < D; i += 256) o[i] = f2b(x[i] * inv);
}

// =============== MX-fp8 MFMA GEMM: C = scale*(A @ B^T) [+bias][*rsqrt(rn)] ==========
// 128x128 tile, BK=128, 16-B-chunk XOR swizzle (2-way LDS aliasing = free, m136).
// No forced min-waves: let the allocator avoid spills (R4 theory: (256,3) spilled).
template<typename OutT, bool NGUARD, bool SUMSQ, bool ROWSCALE>
__global__ __launch_bounds__(256) void gemm_f8(
    const uint8_t* __restrict__ A, const uint8_t* __restrict__ B,
    const float* __restrict__ bias, float* __restrict__ rn, OutT* __restrict__ C,
    int M, int N, int K, int Nld, float scale)
{
    __shared__ alignas(16) uint8_t As[128 * 128];
    __shared__ alignas(16) uint8_t Bs[128 * 128];
    const int id = threadIdx.x;
    const int wave = id >> 6, lane = id & 63;

    // XCD-aware swizzle: all col-blocks of one row-panel -> same XCD
    int bxi = blockIdx.x, byi = blockIdx.y;
    if ((gridDim.y & 7) == 0) {
        int i = byi * gridDim.x + bxi;
        int xcd = i & 7;
        int j = i >> 3;
        bxi = j % gridDim.x;
        byi = xcd + 8 * (j / gridDim.x);
    }
    const int row0 = byi * 128, col0 = bxi * 128;
    const int wm = (wave >> 1) * 64, wn = (wave & 1) * 64;

    // staging: dest chunk f = id + 256t; row = fr + 32t, dest seg = id&7 (t-invariant)
    // source seg = destseg ^ (row&7); row&7 == fr&7 (32t == 0 mod 8)
    const int fr = id >> 3;
    const int fss = (id & 7) ^ (fr & 7);
    const size_t tstride = (size_t)32 * K;          // uniform -> SGPR
    const uint8_t* Ag = A + (size_t)(row0 + fr) * K + fss * 16;
    const uint8_t* Bg;
    const uint8_t* Bgp[4];
    if constexpr (NGUARD) {
        #pragma unroll
        for (int t = 0; t < 4; t++)
            Bgp[t] = B + (size_t)min(col0 + fr + 32 * t, N - 1) * K + fss * 16;
    } else {
        Bg = B + (size_t)(col0 + fr) * K + fss * 16;
    }

    floatx4 acc[4][4] = {};
    const int mrow = lane & 15;
    const int g2 = (lane >> 4) * 2;

    for (int k0 = 0; k0 < K; k0 += 128) {
        #pragma unroll
        for (int t = 0; t < 4; t++) {
            gl_lds16(Ag + k0 + tstride * t, &As[id * 16 + 4096 * t]);
            if constexpr (NGUARD) gl_lds16(Bgp[t] + k0, &Bs[id * 16 + 4096 * t]);
            else                  gl_lds16(Bg + k0 + tstride * t, &Bs[id * 16 + 4096 * t]);
        }
        __syncthreads();
        int8v a[4], b[4];
        #pragma unroll
        for (int i = 0; i < 4; i++) {
            int r = wm + i * 16 + mrow, rs = r & 7;
            int4v lo = *(const int4v*)&As[r * 128 + ((g2    ) ^ rs) * 16];
            int4v hi = *(const int4v*)&As[r * 128 + ((g2 + 1) ^ rs) * 16];
            a[i] = __builtin_shufflevector(lo, hi, 0, 1, 2, 3, 4, 5, 6, 7);
        }
        #pragma unroll
        for (int j = 0; j < 4; j++) {
            int r = wn + j * 16 + mrow, rs = r & 7;
            int4v lo = *(const int4v*)&Bs[r * 128 + ((g2    ) ^ rs) * 16];
            int4v hi = *(const int4v*)&Bs[r * 128 + ((g2 + 1) ^ rs) * 16];
            b[j] = __builtin_shufflevector(lo, hi, 0, 1, 2, 3, 4, 5, 6, 7);
        }
        #pragma unroll
        for (int i = 0; i < 4; i++)
            #pragma unroll
            for (int j = 0; j < 4; j++)
                acc[i][j] = __builtin_amdgcn_mfma_scale_f32_16x16x128_f8f6f4(
                    a[i], b[j], acc[i][j], 0, 0, 0, 0x7f7f7f7f, 0, 0x7f7f7f7f);
        __syncthreads();
    }

    const int ccol0 = col0 + wn + (lane & 15);
    const int crow0 = row0 + wm + (lane >> 4) * 4;
    float bv[4];
    #pragma unroll
    for (int j = 0; j < 4; j++) {
        int col = ccol0 + j * 16;
        bv[j] = (bias && (!NGUARD || col < N)) ? bias[col] : 0.0f;
    }
    #pragma unroll
    for (int i = 0; i < 4; i++) {
        #pragma unroll
        for (int r = 0; r < 4; r++) {
            const int row = crow0 + i * 16 + r;
            float inv = 1.0f;
            if constexpr (ROWSCALE) inv = rsqrtf(rn[row]);
            float ss = 0.0f;
            #pragma unroll
            for (int j = 0; j < 4; j++) {
                int col = ccol0 + j * 16;
                float v = acc[i][j][r] * scale * inv + bv[j];
                if constexpr (SUMSQ) ss += v * v;
                if (!NGUARD || col < N) {
                    if constexpr (sizeof(OutT) == 1)      C[(size_t)row * Nld + col] = (OutT)f2fp8(v);
                    else if constexpr (sizeof(OutT) == 2) C[(size_t)row * Nld + col] = (OutT)f2b(v);
                    else                                   C[(size_t)row * Nld + col] = v;
                }
            }
            if constexpr (SUMSQ) {
                #pragma unroll
                for (int m = 1; m < 16; m <<= 1) ss += __shfl_xor(ss, m, 64);
                if ((lane & 15) == 0) atomicAdd(&rn[row], ss);
            }
        }
    }
}

// ======== bf16 MFMA GEMM (m97 structure): scores = scale*(A @ B^T), bf16 out ========
__global__ __launch_bounds__(256, 4) void gemm_bt_s(
    const ushort* __restrict__ A, const ushort* __restrict__ B,
    ushort* __restrict__ C, int M, int N, int K, float scale)
{
    __shared__ alignas(16) ushort As[128 * 32];
    __shared__ alignas(16) ushort Bs[128 * 32];
    const int id = threadIdx.x;
    const int wave = id >> 6, lane = id & 63;

    int bxi = blockIdx.x, byi = blockIdx.y;
    if ((gridDim.y & 7) == 0) {
        int i = byi * gridDim.x + bxi;
        int xcd = i & 7;
        int j = i >> 3;
        bxi = j % gridDim.x;
        byi = xcd + 8 * (j / gridDim.x);
    }
    const int row0 = byi * 128, col0 = bxi * 128;
    const int wm = (wave >> 1) * 64, wn = (wave & 1) * 64;

    const int f0 = id, f1 = id + 256;
    const int ar0 = f0 >> 2, as0 = (f0 & 3) * 8;
    const int ar1 = f1 >> 2, as1 = (f1 & 3) * 8;

    const ushort* Ag0 = A + (size_t)(row0 + ar0) * K + as0;
    const ushort* Ag1 = A + (size_t)(row0 + ar1) * K + as1;
    const ushort* Bg0 = B + (size_t)(col0 + ar0) * K + as0;
    const ushort* Bg1 = B + (size_t)(col0 + ar1) * K + as1;

    floatx4 acc[4][4] = {};
    const int mrow = lane & 15, koff = (lane >> 4) * 8;

    for (int k0 = 0; k0 < K; k0 += 32) {
        gl_lds16(Ag0 + k0, &As[f0 * 8]);
        gl_lds16(Ag1 + k0, &As[f1 * 8]);
        gl_lds16(Bg0 + k0, &Bs[f0 * 8]);
        gl_lds16(Bg1 + k0, &Bs[f1 * 8]);
        __syncthreads();
        short8 a[4], b[4];
        #pragma unroll
        for (int i = 0; i < 4; i++)
            a[i] = *(const short8*)&As[(wm + i * 16 + mrow) * 32 + koff];
        #pragma unroll
        for (int j = 0; j < 4; j++)
            b[j] = *(const short8*)&Bs[(wn + j * 16 + mrow) * 32 + koff];
        #pragma unroll
        for (int i = 0; i < 4; i++)
            #pragma unroll
            for (int j = 0; j < 4; j++)
                acc[i][j] = __builtin_amdgcn_mfma_f32_16x16x32_bf16(a[i], b[j], acc[i][j], 0, 0, 0);
        __syncthreads();
    }

    const int ccol0 = col0 + wn + (lane & 15);
    const int crow0 = row0 + wm + (lane >> 4) * 4;
    #pragma unroll
    for (int i = 0; i < 4; i++)
        #pragma unroll
        for (int r = 0; r < 4; r++) {
            const int row = crow0 + i * 16 + r;
            #pragma unroll
            for (int j = 0; j < 4; j++)
                C[(size_t)row * N + ccol0 + j * 16] = f2b(acc[i][j][r] * scale);
        }
}

// ------------- fused concept GEMMs (bf16): kmat=c@WkT^T (bf16 out), sim=c@c^T -------
__global__ __launch_bounds__(256) void gemm_concepts(
    const ushort* __restrict__ cbf, const ushort* __restrict__ WkT,
    ushort* __restrict__ kmat, float* __restrict__ sim)
{
    __shared__ alignas(16) ushort As[128 * 32];
    __shared__ alignas(16) ushort Bs[128 * 32];
    const int K = 1024;
    const int id = threadIdx.x;
    const int wave = id >> 6, lane = id & 63;
    const bool issim = blockIdx.x >= 8;
    const ushort* B = issim ? cbf : WkT;
    const int col0 = (issim ? (int)blockIdx.x - 8 : (int)blockIdx.x) * 128;
    const int row0 = blockIdx.y * 128;
    const int wm = (wave >> 1) * 64, wn = (wave & 1) * 64;

    const int f0 = id, f1 = id + 256;
    const int ar0 = f0 >> 2, as0 = (f0 & 3) * 8;
    const int ar1 = f1 >> 2, as1 = (f1 & 3) * 8;

    const ushort* Ag0 = cbf + (size_t)(row0 + ar0) * K + as0;
    const ushort* Ag1 = cbf + (size_t)(row0 + ar1) * K + as1;
    const ushort* Bg0 = B + (size_t)(col0 + ar0) * K + as0;
    const ushort* Bg1 = B + (size_t)(col0 + ar1) * K + as1;

    floatx4 acc[4][4] = {};
    const int mrow = lane & 15, koff = (lane >> 4) * 8;

    for (int k0 = 0; k0 < K; k0 += 32) {
        gl_lds16(Ag0 + k0, &As[f0 * 8]);
        gl_lds16(Ag1 + k0, &As[f1 * 8]);
        gl_lds16(Bg0 + k0, &Bs[f0 * 8]);
        gl_lds16(Bg1 + k0, &Bs[f1 * 8]);
        __syncthreads();
        short8 a[4], b[4];
        #pragma unroll
        for (int i = 0; i < 4; i++)
            a[i] = *(const short8*)&As[(wm + i * 16 + mrow) * 32 + koff];
        #pragma unroll
        for (int j = 0; j < 4; j++)
            b[j] = *(const short8*)&Bs[(wn + j * 16 + mrow) * 32 + koff];
        #pragma unroll
        for (int i = 0; i < 4; i++)
            #pragma unroll
            for (int j = 0; j < 4; j++)
                acc[i][j] = __builtin_amdgcn_mfma_f32_16x16x32_bf16(a[i], b[j], acc[i][j], 0, 0, 0);
        __syncthreads();
    }

    const int ccol0 = col0 + wn + (lane & 15);
    const int crow0 = row0 + wm + (lane >> 4) * 4;
    #pragma unroll
    for (int i = 0; i < 4; i++)
        #pragma unroll
        for (int r = 0; r < 4; r++) {
            const int row = crow0 + i * 16 + r;
            #pragma unroll
            for (int j = 0; j < 4; j++) {
                int col = ccol0 + j * 16;
                float v = acc[i][j][r];
                if (issim) sim[(size_t)row * 512 + col] = v;
                else       kmat[(size_t)row * 1024 + col] = f2b(v);
            }
        }
}

// --- sparsemax rows of 512: bf16 scores in -> f32 attn (d_out) + fp8(x32) copy ------
__global__ __launch_bounds__(256) void sparsemax_k(const ushort* __restrict__ Sb,
                                                   float* __restrict__ attn,
                                                   uint8_t* __restrict__ A8) {
    int wave = threadIdx.x >> 6, lane = threadIdx.x & 63;
    int row = blockIdx.x * 4 + wave;
    const ushort* z = Sb + (size_t)row * 512;
    float v[8];
    #pragma unroll
    for (int j = 0; j < 8; j++) v[j] = b2f(z[lane + 64 * j]);
    float mx = v[0];
    #pragma unroll
    for (int j = 1; j < 8; j++) mx = fmaxf(mx, v[j]);
    #pragma unroll
    for (int off = 1; off < 64; off <<= 1) mx = fmaxf(mx, __shfl_xor(mx, off, 64));
    float lo = mx - 1.0f, hi = mx;
    for (int it = 0; it < 30; it++) {
        float tau = 0.5f * (lo + hi);
        float s = 0.0f;
        #pragma unroll
        for (int j = 0; j < 8; j++) s += fmaxf(v[j] - tau, 0.0f);
        #pragma unroll
        for (int off = 1; off < 64; off <<= 1) s += __shfl_xor(s, off, 64);
        if (s >= 1.0f) lo = tau; else hi = tau;
    }
    float tau = 0.5f * (lo + hi);
    float* of = attn + (size_t)row * 512;
    uint8_t* o8 = A8 + (size_t)row * 512;
    #pragma unroll
    for (int j = 0; j < 8; j++) {
        float o = fmaxf(v[j] - tau, 0.0f);
        of[lane + 64 * j] = o;
        o8[lane + 64 * j] = f2fp8(o * 32.0f);
    }
}

extern "C" void kernel_launch(void* const* d_in, const int* in_sizes, int n_in,
                              void* d_out, int out_size, void* d_ws, size_t ws_size,
                              hipStream_t stream) {
    const float* x        = (const float*)d_in[0];
    const float* concepts = (const float*)d_in[1];
    const float* Wq       = (const float*)d_in[2];
    const float* Wk       = (const float*)d_in[3];
    const float* fc_w     = (const float*)d_in[4];
    const float* fc_b     = (const float*)d_in[5];

    const int B = 16384, D = 1024, C = 512, N = 1000;

    float* out  = (float*)d_out;                       // [B,N]
    float* attn = out + (size_t)B * N;                 // [B,C]
    float* sim  = attn + (size_t)B * C;                // [C,C]

    // ---- ws layout (<63 MiB; overlapped lifetimes disjoint in time) ----
    uint8_t* w = (uint8_t*)d_ws;
    uint8_t* x_f8     = w;                              // [B,D] fp8 16 MiB (dead after q)
    ushort*  score_bf = (ushort*)w;                     // [B,C] bf16 16 MiB (after x dead)
    ushort*  q_bf     = (ushort*)(w + (16ull << 20));   // [B,D] bf16 32 MiB (dead after scores)
    uint8_t* summary  = w + (16ull << 20);              // [B,D] fp8 16 MiB (reuse q region)
    uint8_t* attn_f8  = w + (48ull << 20);              // [B,C] fp8  8 MiB
    uint8_t* WqT_f8   = w + (56ull << 20);              // [D,D]      1 MiB
    ushort*  WkT      = (ushort*)(w + (57ull << 20));   // [D,D] bf16 2 MiB
    ushort*  c_bf     = (ushort*)(w + (59ull << 20));   // [C,D] bf16 1 MiB
    uint8_t* cT_f8    = w + (60ull << 20);              // [D,C] fp8 0.5 MiB
    ushort*  kmat_bf  = (ushort*)(w + (61ull << 20));   // [C,D] bf16 1 MiB
    uint8_t* fcw_f8   = w + (62ull << 20);              // [N,D] fp8  1 MiB
    float*   rn       = (float*)(w + (63ull << 20));    // [B]       64 KiB

    // scales: x*1, Wq*16 -> q scale 1/16 (bf16 out, true scale)
    //         attn*32, c*16 -> summary scale 1/8 => stores 64*summary; rn = (64)^2*||s||^2
    //         summary*64, fcw*16 -> fc scale 1/16, *rsqrt(rn) cancels the 64

    // 1. x -> fp8 ; WqT -> fp8(*16) ; q = x @ Wq (bf16 out)
    convert_f32_fp8<<<(B * D / 4 + 255) / 256, 256, 0, stream>>>(x, x_f8, B * D / 4, 1.0f);
    transpose_f32_to_fp8<<<dim3(D / 32, D / 32), 256, 0, stream>>>(Wq, WqT_f8, D, D, 16.0f);
    gemm_f8<ushort, false, false, false><<<dim3(D / 128, B / 128), 256, 0, stream>>>(
        x_f8, WqT_f8, nullptr, nullptr, q_bf, B, D, D, D, 1.0f / 16.0f);
    // 2. concepts pipeline
    normalize_f32_to_bf16<<<C, 256, 0, stream>>>(concepts, c_bf, D);
    transpose_f32_to_bf16<<<dim3(D / 32, D / 32), 256, 0, stream>>>(Wk, WkT, D, D);
    transpose_bf16_to_fp8<<<dim3(D / 32, C / 32), 256, 0, stream>>>(c_bf, cT_f8, C, D, 16.0f);
    gemm_concepts<<<dim3(12, C / 128), 256, 0, stream>>>(c_bf, WkT, kmat_bf, sim);
    // 3. scores = (q @ k^T)/32, bf16 MFMA, bf16 out into x_f8 region
    gemm_bt_s<<<dim3(C / 128, B / 128), 256, 0, stream>>>(
        q_bf, kmat_bf, score_bf, B, C, D, 0.03125f);
    // 4. sparsemax: bf16 scores -> f32 attn (d_out) + fp8(*32)
    sparsemax_k<<<B / 4, 256, 0, stream>>>(score_bf, attn, attn_f8);
    // 5. fc weights -> fp8(*16)
    convert_f32_fp8<<<(N * D / 4 + 255) / 256, 256, 0, stream>>>(fc_w, fcw_f8, N * D / 4, 16.0f);
    // 6. summary = attn @ c (fp8 *64 into q region) + per-row sumsq
    hipMemsetAsync(rn, 0, B * sizeof(float), stream);
    gemm_f8<uint8_t, false, true, false><<<dim3(D / 128, B / 128), 256, 0, stream>>>(
        attn_f8, cT_f8, nullptr, rn, summary, B, D, C, D, 1.0f / 8.0f);
    // 7. out = (summary * rsqrt(rn)) @ fc_w^T + fc_b
    gemm_f8<float, true, false, true><<<dim3((N + 127) / 128, B / 128), 256, 0, stream>>>(
        summary, fcw_f8, fc_b, rn, out, B, N, D, N, 1.0f / 16.0f);
}